// Round 20
// baseline (183.543 us; speedup 1.0000x reference)
//
#include <hip/hip_runtime.h>

#define Bsz   32
#define Hh    8
#define Ww    128
#define Cc    512
#define NHEAD 8
#define HD    64
#define NN    1024
#define SCALE 0.125f
#define ROWS  1536
#define ROWSP 1568   // padded qkv row stride (halfs): 3136B -> L1 set-step 49, full coverage

typedef _Float16 f16x8 __attribute__((ext_vector_type(8)));
typedef float    f32x4 __attribute__((ext_vector_type(4)));

// ---------------------------------------------------------------------------
// async global->LDS, 16B per lane (linear dest = wave base + lane*16)
// ---------------------------------------------------------------------------
__device__ __forceinline__ void gload16(const _Float16* g, _Float16* l) {
#if __has_builtin(__builtin_amdgcn_global_load_lds)
  __builtin_amdgcn_global_load_lds(
      (const __attribute__((address_space(1))) unsigned int*)g,
      (__attribute__((address_space(3))) unsigned int*)l, 16, 0, 0);
#else
  *(uint4*)l = *(const uint4*)g;
#endif
}

// ---------------------------------------------------------------------------
// converts
// ---------------------------------------------------------------------------
__global__ __launch_bounds__(256) void cvt_f32_f16(
    const float* __restrict__ in, _Float16* __restrict__ out, int n8) {
  const int i = blockIdx.x * 256 + threadIdx.x;
  if (i < n8) {
    const float4 f0 = ((const float4*)in)[(size_t)i * 2];
    const float4 f1 = ((const float4*)in)[(size_t)i * 2 + 1];
    union { _Float16 h[8]; uint4 u; } pk;
    pk.h[0] = (_Float16)f0.x; pk.h[1] = (_Float16)f0.y;
    pk.h[2] = (_Float16)f0.z; pk.h[3] = (_Float16)f0.w;
    pk.h[4] = (_Float16)f1.x; pk.h[5] = (_Float16)f1.y;
    pk.h[6] = (_Float16)f1.z; pk.h[7] = (_Float16)f1.w;
    ((uint4*)out)[i] = pk.u;
  }
}

// out[n*K + k] = in[k*Nn + n]  (f32 -> f16 transpose)
__global__ __launch_bounds__(256) void tcvt(
    const float* __restrict__ in, _Float16* __restrict__ out, int Nn, int K) {
  const int id = blockIdx.x * 256 + threadIdx.x;
  if (id < Nn * K) {
    const int n = id / K, k = id - n * K;
    out[id] = (_Float16)in[(size_t)k * Nn + n];
  }
}

// ---------------------------------------------------------------------------
// MFMA GEMM, 256x256 tile, BK=32, 8 waves of 128x64 each, 2-phase dbuf LDS.
// Round-19 cycle accounting: the old 128x256 (64x64/wave) kernel was LDS-
// READ-THROUGHPUT bound -- 8 b128 reads per 16 MFMA (6 cyc LDS per 4.85 cyc
// MFMA) plus 8-way bank conflicts on the linear [row][32] layout (6.3M
// conflict cycles). Fixes:
//  (1) 128x64 per wave: 12 reads per 32 MFMA -> 4.5 cyc/MFMA < 4.85 ->
//      MFMA-bound by construction. acc[8][4] = 128 VGPR, 1 block/CU.
//  (2) chunk swizzle (both-sides, rule 21): stage chunk (row,k4) from global
//      k-chunk k4 ^ ((row>>1)&3) via pre-swizzled source (dest stays linear
//      for global_load_lds); fragment reads XOR the same term -- per-lane
//      constant (rA fixed/lane), residual conflicts exactly 2-way (free).
// Sync = r18-proven: stage(t+1) at top, __syncthreads at bottom.
// 1D grid (768/256 blocks -- %8==0) + XCD-chunked bijective swizzle.
// ---------------------------------------------------------------------------
template<bool OUT_F16, bool HAS_BIAS>
__global__ __launch_bounds__(512, 2) void gemm_mfma(
    const _Float16* __restrict__ A,
    const _Float16* __restrict__ BT,
    const float* __restrict__ bias,
    void* __restrict__ Cout,
    int nbx, int Nn, int K, int ldc)
{
  __shared__ _Float16 As[2][256 * 32];   // 16KB per buf
  __shared__ _Float16 Bs[2][256 * 32];   // 16KB per buf

  const int wg    = blockIdx.x;
  const int chunk = gridDim.x >> 3;
  const int nid   = (wg & 7) * chunk + (wg >> 3);
  const int bn    = (nid % nbx) * 256;
  const int bm    = (nid / nbx) * 256;

  const int t  = threadIdx.x;
  const int l  = t & 63, wv = t >> 6;
  const int wr = wv >> 2, wc = wv & 3;   // 2M x 4N wave grid; 128x64 per wave

  f32x4 acc[8][4] = {};

  // staging: A,B each 1024 chunks of 16B; 2 A + 2 B chunks per thread.
  // chunk c: row = c>>2, k4 = c&3; source k-chunk = k4 ^ ((row>>1)&3).
  auto stage = [&](int k0, int pb) {
#pragma unroll
    for (int q = 0; q < 2; ++q) {
      const int c   = t + q * 512;
      const int row = c >> 2, k4 = c & 3;
      const int ks  = (k4 ^ ((row >> 1) & 3)) << 3;
      gload16(A  + (size_t)(bm + row) * K + k0 + ks, &As[pb][c * 8]);
      gload16(BT + (size_t)(bn + row) * K + k0 + ks, &Bs[pb][c * 8]);
    }
  };

  const int nt = K / 32;                 // 16

  stage(0, 0);
  __syncthreads();

  const int rA   = l & 15;
  const int kofs = ((l >> 4) * 8) ^ (((rA >> 1) & 3) << 3);  // per-lane const

  int buf = 0;
  for (int tt = 0; tt < nt; ++tt) {
    if (tt + 1 < nt) stage((tt + 1) * 32, buf ^ 1);   // in flight under compute

    f16x8 bF[4];
#pragma unroll
    for (int jj = 0; jj < 4; ++jj)
      bF[jj] = *(const f16x8*)&Bs[buf][(wc * 64 + jj * 16 + rA) * 32 + kofs];
#pragma unroll
    for (int i = 0; i < 8; ++i) {
      const f16x8 aF = *(const f16x8*)&As[buf][(wr * 128 + i * 16 + rA) * 32 + kofs];
#pragma unroll
      for (int jj = 0; jj < 4; ++jj)
        acc[i][jj] = __builtin_amdgcn_mfma_f32_16x16x32_f16(aF, bF[jj], acc[i][jj], 0, 0, 0);
    }

    __syncthreads();                     // staging(t+1) drained; buf readers done
    buf ^= 1;
  }

  const int lc = l & 15, lr4 = (l >> 4) * 4;
#pragma unroll
  for (int i = 0; i < 8; ++i) {
    const size_t row0 = (size_t)(bm + wr * 128 + i * 16 + lr4);
#pragma unroll
    for (int jj = 0; jj < 4; ++jj) {
      const int col = bn + wc * 64 + jj * 16 + lc;
      const float bv = HAS_BIAS ? bias[col] : 0.f;
#pragma unroll
      for (int r = 0; r < 4; ++r) {
        const float v = acc[i][jj][r] + bv;
        if (OUT_F16)
          ((_Float16*)Cout)[(row0 + r) * ldc + col] = (_Float16)v;
        else
          ((float*)Cout)[(row0 + r) * ldc + col] = v;
      }
    }
  }
}

// ---------------------------------------------------------------------------
// MFMA local attention, h-paired (1024 blocks) + XCD-chunked. ALL per-wave
// fragment reads come from LDS (K via swizzled global_load_lds, V reg-
// transposed to Vsh[64][132]) -- round 18 verified this removes the L1
// scattered-fragment bottleneck. qkv rows padded to ROWSP=1568 halfs for
// full L1-set coverage. Swapped-QK (lane-local softmax rows, mask as
// additive bias) + max-free softmax (P=exp(min(S,11)), one epilogue reduce).
// No fences; Pbuf wave-private. UNCHANGED from r18 (the verified config).
// ---------------------------------------------------------------------------
__global__ __launch_bounds__(512, 4) void local_attn_mfma(
    const _Float16* __restrict__ qkv, _Float16* __restrict__ outh)
{
  const int wg  = blockIdx.x;                 // 1024, 1-D
  const int nid = ((wg & 7) << 7) + (wg >> 3);
  const int hp = nid & 3, head = (nid >> 2) & 7, b = nid >> 5;
  const int h0 = hp * 2;

  const int t = threadIdx.x;
  const int wv = t >> 6, l = t & 63;
  const int g = l >> 4, c = l & 15;
  const int w0 = wv * 16;                     // wave's query-col tile base
  const int kb = min(max(w0 - 8, 0), 96);     // 8-aligned key tile base

  __shared__ _Float16 Ksh[8192];              // 128 cols x 64 halfs, chunk-swz
  __shared__ _Float16 Vsh[64 * 132];          // [d][132-pad cols]
  __shared__ _Float16 Pbuf[8][576];           // [wave][q*36 + kcol]

  const _Float16* qb = qkv + (size_t)b * NN * ROWSP;

  // ---- Q fragments (lane c holds Q[w0+c][k-slice]; used as B-operand) ----
  f16x8 qF[2][2];
#pragma unroll
  for (int hi = 0; hi < 2; ++hi) {
    const _Float16* Qg = qb + (size_t)((h0 + hi) * Ww + w0 + c) * ROWSP + head * HD;
    qF[hi][0] = *(const f16x8*)&Qg[g * 8];
    qF[hi][1] = *(const f16x8*)&Qg[32 + g * 8];
  }

  // ---- additive mask bias: kcol = kb+16tt+4g+r vs q = w0+c (h-indep) ----
  float mbias[2][4];
#pragma unroll
  for (int tt = 0; tt < 2; ++tt)
#pragma unroll
    for (int r = 0; r < 4; ++r) {
      const int kcol = kb + 16 * tt + 4 * g + r;
      const int qq   = w0 + c;
      mbias[tt][r] = (kcol >= qq - 5 && kcol <= qq + 5) ? 0.f : -1e30f;
    }

  const int r0 = max(0, h0 - 3), r1 = min(Hh - 1, h0 + 4);
  float s_part[2] = {0.f, 0.f};               // per-lane partial exp-sums
  f32x4 accO[2][4] = {};

  // V staging coords (threads t>=256: 4 cols x 8 d each)
  const int dd = t & 7, cg = (t & 255) >> 3;

  for (int kr = r0; kr <= r1; ++kr) {
    __syncthreads();                          // prev compute done with Ksh/Vsh
    if (t < 256) {
      const _Float16* Kg = qb + (size_t)(kr * Ww) * ROWSP + Cc + head * HD;
#pragma unroll
      for (int i = 0; i < 4; ++i) {
        const int o   = (i * 4 + wv) * 64 + l;       // linear chunk 0..1023
        const int col = o >> 3, dc = o & 7;
        gload16(Kg + (size_t)col * ROWSP + ((dc ^ (col & 7)) << 3), &Ksh[o * 8]);
      }
    } else {
      f16x8 vr[4];
      const _Float16* Vg = qb + (size_t)(kr * Ww + cg * 4) * ROWSP + 2 * Cc + head * HD + dd * 8;
#pragma unroll
      for (int i = 0; i < 4; ++i)
        vr[i] = *(const f16x8*)&Vg[(size_t)i * ROWSP];
#pragma unroll
      for (int e = 0; e < 8; ++e) {
        union { _Float16 hh[4]; uint2 u; } pk;
        pk.hh[0] = vr[0][e]; pk.hh[1] = vr[1][e];
        pk.hh[2] = vr[2][e]; pk.hh[3] = vr[3][e];
        *(uint2*)&Vsh[(dd * 8 + e) * 132 + cg * 4] = pk.u;
      }
    }
    __syncthreads();                          // Ksh/Vsh published (vmcnt+lgkm)

#pragma unroll
    for (int hi = 0; hi < 2; ++hi) {
      const int hq = h0 + hi;
      if (kr < hq - 3 || kr > hq + 3) continue;

      // ---- swapped QK^T from LDS: Ssw[kcol_local=4g+r (+16tt)][q=c] ----
      f32x4 accS[2] = {};
      __builtin_amdgcn_s_setprio(1);
#pragma unroll
      for (int tt = 0; tt < 2; ++tt) {
        const int col = kb + 16 * tt + c;
#pragma unroll
        for (int s = 0; s < 2; ++s) {
          const f16x8 kF = *(const f16x8*)&Ksh[col * 64 + (((s * 4 + g) ^ (c & 7)) << 3)];
          accS[tt] = __builtin_amdgcn_mfma_f32_16x16x32_f16(kF, qF[hi][s], accS[tt], 0, 0, 0);
        }
      }
      __builtin_amdgcn_s_setprio(0);

      // ---- max-free softmax: P = exp(min(S,11)), per-lane partial sum ----
#pragma unroll
      for (int tt = 0; tt < 2; ++tt) {
        float p0 = __expf(fminf(__builtin_fmaf(accS[tt][0], SCALE, mbias[tt][0]), 11.f));
        float p1 = __expf(fminf(__builtin_fmaf(accS[tt][1], SCALE, mbias[tt][1]), 11.f));
        float p2 = __expf(fminf(__builtin_fmaf(accS[tt][2], SCALE, mbias[tt][2]), 11.f));
        float p3 = __expf(fminf(__builtin_fmaf(accS[tt][3], SCALE, mbias[tt][3]), 11.f));
        s_part[hi] += (p0 + p1) + (p2 + p3);
        union { _Float16 hh[4]; uint2 u; } pk;
        pk.hh[0] = (_Float16)p0; pk.hh[1] = (_Float16)p1;
        pk.hh[2] = (_Float16)p2; pk.hh[3] = (_Float16)p3;
        *(uint2*)&Pbuf[wv][c * 36 + 16 * tt + 4 * g] = pk.u;
      }

      // ---- PV: O[q=4g+r][d=16jj+c] += P(16x32) * V(32x64-window) ----
      union { f16x8 v; uint2 u2[2]; } pF;
      {
        const _Float16* pp = &Pbuf[wv][c * 36 + g * 8];
        pF.u2[0] = *(const uint2*)pp;
        pF.u2[1] = *(const uint2*)(pp + 4);
      }
      __builtin_amdgcn_s_setprio(1);
#pragma unroll
      for (int jj = 0; jj < 4; ++jj) {
        union { f16x8 v; uint2 u2[2]; } vF;
        const _Float16* vp = &Vsh[(16 * jj + c) * 132 + kb + g * 8];
        vF.u2[0] = *(const uint2*)vp;
        vF.u2[1] = *(const uint2*)(vp + 4);
        accO[hi][jj] = __builtin_amdgcn_mfma_f32_16x16x32_f16(pF.v, vF.v, accO[hi][jj], 0, 0, 0);
      }
      __builtin_amdgcn_s_setprio(0);
    }
  }

  // ---- epilogue: one cross-lane reduce per hi, normalize, store ----
#pragma unroll
  for (int hi = 0; hi < 2; ++hi) {
    float s_run = s_part[hi];
    s_run += __shfl_xor(s_run, 16);
    s_run += __shfl_xor(s_run, 32);           // lanes (.,c) hold sum for query c
    _Float16* ob = outh + ((size_t)b * NN + (h0 + hi) * Ww + w0) * Cc + head * HD;
#pragma unroll
    for (int r = 0; r < 4; ++r) {
      const float sr  = __shfl(s_run, 4 * g + r, 16);
      const float inv = 1.f / sr;
      const int q = 4 * g + r;
#pragma unroll
      for (int jj = 0; jj < 4; ++jj)
        ob[(size_t)q * Cc + 16 * jj + c] = (_Float16)(accO[hi][jj][r] * inv);
    }
  }
}

// ---------------------------------------------------------------------------
extern "C" void kernel_launch(void* const* d_in, const int* in_sizes, int n_in,
                              void* d_out, int out_size, void* d_ws, size_t ws_size,
                              hipStream_t stream)
{
  const float* x      = (const float*)d_in[0];   // [32,1024,512]
  const float* w_qkv  = (const float*)d_in[1];   // [512,1536]
  const float* w_proj = (const float*)d_in[2];   // [512,512]
  const float* b_proj = (const float*)d_in[3];   // [512]
  float* out = (float*)d_out;

  const int M = Bsz * NN;                        // 32768
  char* ws = (char*)d_ws;
  _Float16* xh    = (_Float16*)ws;                              // 33.55 MB
  _Float16* qkvh  = (_Float16*)(ws + 33554432);                 // 102.76 MB (1568-padded rows)
  _Float16* attnh = (_Float16*)(ws + 136314880);                // 33.55 MB
  _Float16* wqT   = (_Float16*)(ws + 169869312);                // 1.57 MB
  _Float16* wpT   = (_Float16*)(ws + 171442176);                // 0.52 MB

  // converts
  cvt_f32_f16<<<(M * Cc / 8 + 255) / 256, 256, 0, stream>>>(x, xh, M * Cc / 8);
  tcvt<<<(ROWS * Cc + 255) / 256, 256, 0, stream>>>(w_qkv, wqT, ROWS, Cc);
  tcvt<<<(Cc * Cc + 255) / 256, 256, 0, stream>>>(w_proj, wpT, Cc, Cc);

  // qkv = x @ w_qkv  (f16; 256x256 tiles: 6x128 = 768 blocks, XCD-chunked;
  // ldc = 1568 padded)
  gemm_mfma<true, false><<<(ROWS / 256) * (M / 256), 512, 0, stream>>>(
      xh, wqT, nullptr, qkvh, ROWS / 256, ROWS, Cc, ROWSP);

  // local attention (h-paired, LDS-staged K/V, swapped max-free softmax)
  local_attn_mfma<<<(Hh / 2) * NHEAD * Bsz, 512, 0, stream>>>(qkvh, attnh);

  // out = attn @ w_proj + bias  (f32 out; 2x128 = 256 blocks, XCD-chunked)
  gemm_mfma<false, true><<<(Cc / 256) * (M / 256), 512, 0, stream>>>(
      attnh, wpT, b_proj, out, Cc / 256, Cc, Cc, Cc);
}

// Round 21
// 166.730 us; speedup vs baseline: 1.1008x; 1.1008x over previous
//
#include <hip/hip_runtime.h>

#define Bsz   32
#define Hh    8
#define Ww    128
#define Cc    512
#define NHEAD 8
#define HD    64
#define NN    1024
#define SCALE 0.125f
#define ROWS  1536
#define ROWSP 1568   // padded qkv row stride (halfs): 3136B -> L1 set-step 49, full coverage

typedef _Float16 f16x8 __attribute__((ext_vector_type(8)));
typedef float    f32x4 __attribute__((ext_vector_type(4)));

// ---------------------------------------------------------------------------
// async global->LDS, 16B per lane (linear dest = wave base + lane*16)
// ---------------------------------------------------------------------------
__device__ __forceinline__ void gload16(const _Float16* g, _Float16* l) {
#if __has_builtin(__builtin_amdgcn_global_load_lds)
  __builtin_amdgcn_global_load_lds(
      (const __attribute__((address_space(1))) unsigned int*)g,
      (__attribute__((address_space(3))) unsigned int*)l, 16, 0, 0);
#else
  *(uint4*)l = *(const uint4*)g;
#endif
}

// ---------------------------------------------------------------------------
// converts
// ---------------------------------------------------------------------------
__global__ __launch_bounds__(256) void cvt_f32_f16(
    const float* __restrict__ in, _Float16* __restrict__ out, int n8) {
  const int i = blockIdx.x * 256 + threadIdx.x;
  if (i < n8) {
    const float4 f0 = ((const float4*)in)[(size_t)i * 2];
    const float4 f1 = ((const float4*)in)[(size_t)i * 2 + 1];
    union { _Float16 h[8]; uint4 u; } pk;
    pk.h[0] = (_Float16)f0.x; pk.h[1] = (_Float16)f0.y;
    pk.h[2] = (_Float16)f0.z; pk.h[3] = (_Float16)f0.w;
    pk.h[4] = (_Float16)f1.x; pk.h[5] = (_Float16)f1.y;
    pk.h[6] = (_Float16)f1.z; pk.h[7] = (_Float16)f1.w;
    ((uint4*)out)[i] = pk.u;
  }
}

// out[n*K + k] = in[k*Nn + n]  (f32 -> f16 transpose)
__global__ __launch_bounds__(256) void tcvt(
    const float* __restrict__ in, _Float16* __restrict__ out, int Nn, int K) {
  const int id = blockIdx.x * 256 + threadIdx.x;
  if (id < Nn * K) {
    const int n = id / K, k = id - n * K;
    out[id] = (_Float16)in[(size_t)k * Nn + n];
  }
}

// ---------------------------------------------------------------------------
// MFMA GEMM, 128(M)x256(N) tile, BK=32, 8 waves (wave grid 2Mx4N, 64x64 per
// wave), 2-phase double-buffered LDS via global_load_lds -- r18's 73.7us
// config -- PLUS r20's verified both-sides chunk swizzle:
//   stage chunk (row, k4) from global k-chunk k4 ^ ((row>>1)&3) (pre-swizzled
//   SOURCE, LDS dest stays linear for global_load_lds);
//   fragment reads XOR the same term: kofs = ks ^ (((rA>>1)&3)<<3), a
//   per-lane constant (row = {wr*64|wc*64} + i*16 + rA keeps (row>>1)&3 ==
//   (rA>>1)&3). Result r20-measured: SQ_LDS_BANK_CONFLICT 6.29M -> 0.
// r20's 256x256 variant killed conflicts but dropped to 1 block/CU (occ 21%,
// no overlap partner) and regressed; this keeps 2 blocks/CU (16 waves).
// Output row stride ldc parameterized (qkv pad). XCD-chunked 1D grid.
// ---------------------------------------------------------------------------
template<bool OUT_F16, bool HAS_BIAS>
__global__ __launch_bounds__(512, 4) void gemm_mfma(
    const _Float16* __restrict__ A,
    const _Float16* __restrict__ BT,
    const float* __restrict__ bias,
    void* __restrict__ Cout,
    int nbx, int Nn, int K, int ldc)
{
  __shared__ _Float16 As[2][128 * 32];   // 8KB per buf
  __shared__ _Float16 Bs[2][256 * 32];   // 16KB per buf

  const int wg    = blockIdx.x;
  const int chunk = gridDim.x >> 3;
  const int nid   = (wg & 7) * chunk + (wg >> 3);
  const int bn    = (nid % nbx) * 256;
  const int bm    = (nid / nbx) * 128;

  const int t  = threadIdx.x;
  const int l  = t & 63, wv = t >> 6;
  const int wr = wv >> 2, wc = wv & 3;

  f32x4 acc[4][4] = {};

  const int arow = t >> 2;            // 0..127
  // swizzled source k-offset for this thread's chunk (row=arow, k4=t&3);
  // (128+arow)>>1 & 3 == (arow>>1)&3, so one term serves both B halves.
  const int acs  = (((t & 3) ^ ((arow >> 1) & 3)) << 3);
  const int adst = arow * 32 + (t & 3) * 8;

  auto stage = [&](int k0, int pb) {
    gload16(A  + (size_t)(bm + arow)       * K + k0 + acs, &As[pb][adst]);
    gload16(BT + (size_t)(bn + arow)       * K + k0 + acs, &Bs[pb][adst]);
    gload16(BT + (size_t)(bn + 128 + arow) * K + k0 + acs, &Bs[pb][4096 + adst]);
  };

  const int nt = K / 32;

  // ---- prologue ----
  stage(0, 0);
  __syncthreads();

  const int rA   = l & 15;
  const int kofs = ((l >> 4) * 8) ^ (((rA >> 1) & 3) << 3);  // per-lane const

  int buf = 0;
  for (int tt = 0; tt < nt; ++tt) {
    if (tt + 1 < nt) stage((tt + 1) * 32, buf ^ 1);   // in flight under compute

    f16x8 aF[4], bF[4];
#pragma unroll
    for (int i = 0; i < 4; ++i)
      aF[i] = *(const f16x8*)&As[buf][(wr * 64 + i * 16 + rA) * 32 + kofs];
#pragma unroll
    for (int j = 0; j < 4; ++j)
      bF[j] = *(const f16x8*)&Bs[buf][(wc * 64 + j * 16 + rA) * 32 + kofs];
#pragma unroll
    for (int i = 0; i < 4; ++i)
#pragma unroll
      for (int j = 0; j < 4; ++j)
        acc[i][j] = __builtin_amdgcn_mfma_f32_16x16x32_f16(aF[i], bF[j], acc[i][j], 0, 0, 0);

    __syncthreads();                   // staging(t+1) drained; buf readers done
    buf ^= 1;
  }

  const int lc = l & 15, lr4 = (l >> 4) * 4;
#pragma unroll
  for (int i = 0; i < 4; ++i) {
    const size_t row0 = (size_t)(bm + wr * 64 + i * 16 + lr4);
#pragma unroll
    for (int j = 0; j < 4; ++j) {
      const int col = bn + wc * 64 + j * 16 + lc;
      const float bv = HAS_BIAS ? bias[col] : 0.f;
#pragma unroll
      for (int r = 0; r < 4; ++r) {
        const float v = acc[i][j][r] + bv;
        if (OUT_F16)
          ((_Float16*)Cout)[(row0 + r) * ldc + col] = (_Float16)v;
        else
          ((float*)Cout)[(row0 + r) * ldc + col] = v;
      }
    }
  }
}

// ---------------------------------------------------------------------------
// MFMA local attention, h-paired (1024 blocks) + XCD-chunked. ALL per-wave
// fragment reads come from LDS (K via swizzled global_load_lds, V reg-
// transposed to Vsh[64][132]) -- round 18 verified this removes the L1
// scattered-fragment bottleneck. qkv rows padded to ROWSP=1568 halfs for
// full L1-set coverage. Swapped-QK (lane-local softmax rows, mask as
// additive bias) + max-free softmax (P=exp(min(S,11)), one epilogue reduce).
// No fences; Pbuf wave-private. UNCHANGED from r18 (the verified config).
// ---------------------------------------------------------------------------
__global__ __launch_bounds__(512, 4) void local_attn_mfma(
    const _Float16* __restrict__ qkv, _Float16* __restrict__ outh)
{
  const int wg  = blockIdx.x;                 // 1024, 1-D
  const int nid = ((wg & 7) << 7) + (wg >> 3);
  const int hp = nid & 3, head = (nid >> 2) & 7, b = nid >> 5;
  const int h0 = hp * 2;

  const int t = threadIdx.x;
  const int wv = t >> 6, l = t & 63;
  const int g = l >> 4, c = l & 15;
  const int w0 = wv * 16;                     // wave's query-col tile base
  const int kb = min(max(w0 - 8, 0), 96);     // 8-aligned key tile base

  __shared__ _Float16 Ksh[8192];              // 128 cols x 64 halfs, chunk-swz
  __shared__ _Float16 Vsh[64 * 132];          // [d][132-pad cols]
  __shared__ _Float16 Pbuf[8][576];           // [wave][q*36 + kcol]

  const _Float16* qb = qkv + (size_t)b * NN * ROWSP;

  // ---- Q fragments (lane c holds Q[w0+c][k-slice]; used as B-operand) ----
  f16x8 qF[2][2];
#pragma unroll
  for (int hi = 0; hi < 2; ++hi) {
    const _Float16* Qg = qb + (size_t)((h0 + hi) * Ww + w0 + c) * ROWSP + head * HD;
    qF[hi][0] = *(const f16x8*)&Qg[g * 8];
    qF[hi][1] = *(const f16x8*)&Qg[32 + g * 8];
  }

  // ---- additive mask bias: kcol = kb+16tt+4g+r vs q = w0+c (h-indep) ----
  float mbias[2][4];
#pragma unroll
  for (int tt = 0; tt < 2; ++tt)
#pragma unroll
    for (int r = 0; r < 4; ++r) {
      const int kcol = kb + 16 * tt + 4 * g + r;
      const int qq   = w0 + c;
      mbias[tt][r] = (kcol >= qq - 5 && kcol <= qq + 5) ? 0.f : -1e30f;
    }

  const int r0 = max(0, h0 - 3), r1 = min(Hh - 1, h0 + 4);
  float s_part[2] = {0.f, 0.f};               // per-lane partial exp-sums
  f32x4 accO[2][4] = {};

  // V staging coords (threads t>=256: 4 cols x 8 d each)
  const int dd = t & 7, cg = (t & 255) >> 3;

  for (int kr = r0; kr <= r1; ++kr) {
    __syncthreads();                          // prev compute done with Ksh/Vsh
    if (t < 256) {
      const _Float16* Kg = qb + (size_t)(kr * Ww) * ROWSP + Cc + head * HD;
#pragma unroll
      for (int i = 0; i < 4; ++i) {
        const int o   = (i * 4 + wv) * 64 + l;       // linear chunk 0..1023
        const int col = o >> 3, dc = o & 7;
        gload16(Kg + (size_t)col * ROWSP + ((dc ^ (col & 7)) << 3), &Ksh[o * 8]);
      }
    } else {
      f16x8 vr[4];
      const _Float16* Vg = qb + (size_t)(kr * Ww + cg * 4) * ROWSP + 2 * Cc + head * HD + dd * 8;
#pragma unroll
      for (int i = 0; i < 4; ++i)
        vr[i] = *(const f16x8*)&Vg[(size_t)i * ROWSP];
#pragma unroll
      for (int e = 0; e < 8; ++e) {
        union { _Float16 hh[4]; uint2 u; } pk;
        pk.hh[0] = vr[0][e]; pk.hh[1] = vr[1][e];
        pk.hh[2] = vr[2][e]; pk.hh[3] = vr[3][e];
        *(uint2*)&Vsh[(dd * 8 + e) * 132 + cg * 4] = pk.u;
      }
    }
    __syncthreads();                          // Ksh/Vsh published (vmcnt+lgkm)

#pragma unroll
    for (int hi = 0; hi < 2; ++hi) {
      const int hq = h0 + hi;
      if (kr < hq - 3 || kr > hq + 3) continue;

      // ---- swapped QK^T from LDS: Ssw[kcol_local=4g+r (+16tt)][q=c] ----
      f32x4 accS[2] = {};
      __builtin_amdgcn_s_setprio(1);
#pragma unroll
      for (int tt = 0; tt < 2; ++tt) {
        const int col = kb + 16 * tt + c;
#pragma unroll
        for (int s = 0; s < 2; ++s) {
          const f16x8 kF = *(const f16x8*)&Ksh[col * 64 + (((s * 4 + g) ^ (c & 7)) << 3)];
          accS[tt] = __builtin_amdgcn_mfma_f32_16x16x32_f16(kF, qF[hi][s], accS[tt], 0, 0, 0);
        }
      }
      __builtin_amdgcn_s_setprio(0);

      // ---- max-free softmax: P = exp(min(S,11)), per-lane partial sum ----
#pragma unroll
      for (int tt = 0; tt < 2; ++tt) {
        float p0 = __expf(fminf(__builtin_fmaf(accS[tt][0], SCALE, mbias[tt][0]), 11.f));
        float p1 = __expf(fminf(__builtin_fmaf(accS[tt][1], SCALE, mbias[tt][1]), 11.f));
        float p2 = __expf(fminf(__builtin_fmaf(accS[tt][2], SCALE, mbias[tt][2]), 11.f));
        float p3 = __expf(fminf(__builtin_fmaf(accS[tt][3], SCALE, mbias[tt][3]), 11.f));
        s_part[hi] += (p0 + p1) + (p2 + p3);
        union { _Float16 hh[4]; uint2 u; } pk;
        pk.hh[0] = (_Float16)p0; pk.hh[1] = (_Float16)p1;
        pk.hh[2] = (_Float16)p2; pk.hh[3] = (_Float16)p3;
        *(uint2*)&Pbuf[wv][c * 36 + 16 * tt + 4 * g] = pk.u;
      }

      // ---- PV: O[q=4g+r][d=16jj+c] += P(16x32) * V(32x64-window) ----
      union { f16x8 v; uint2 u2[2]; } pF;
      {
        const _Float16* pp = &Pbuf[wv][c * 36 + g * 8];
        pF.u2[0] = *(const uint2*)pp;
        pF.u2[1] = *(const uint2*)(pp + 4);
      }
      __builtin_amdgcn_s_setprio(1);
#pragma unroll
      for (int jj = 0; jj < 4; ++jj) {
        union { f16x8 v; uint2 u2[2]; } vF;
        const _Float16* vp = &Vsh[(16 * jj + c) * 132 + kb + g * 8];
        vF.u2[0] = *(const uint2*)vp;
        vF.u2[1] = *(const uint2*)(vp + 4);
        accO[hi][jj] = __builtin_amdgcn_mfma_f32_16x16x32_f16(pF.v, vF.v, accO[hi][jj], 0, 0, 0);
      }
      __builtin_amdgcn_s_setprio(0);
    }
  }

  // ---- epilogue: one cross-lane reduce per hi, normalize, store ----
#pragma unroll
  for (int hi = 0; hi < 2; ++hi) {
    float s_run = s_part[hi];
    s_run += __shfl_xor(s_run, 16);
    s_run += __shfl_xor(s_run, 32);           // lanes (.,c) hold sum for query c
    _Float16* ob = outh + ((size_t)b * NN + (h0 + hi) * Ww + w0) * Cc + head * HD;
#pragma unroll
    for (int r = 0; r < 4; ++r) {
      const float sr  = __shfl(s_run, 4 * g + r, 16);
      const float inv = 1.f / sr;
      const int q = 4 * g + r;
#pragma unroll
      for (int jj = 0; jj < 4; ++jj)
        ob[(size_t)q * Cc + 16 * jj + c] = (_Float16)(accO[hi][jj][r] * inv);
    }
  }
}

// ---------------------------------------------------------------------------
extern "C" void kernel_launch(void* const* d_in, const int* in_sizes, int n_in,
                              void* d_out, int out_size, void* d_ws, size_t ws_size,
                              hipStream_t stream)
{
  const float* x      = (const float*)d_in[0];   // [32,1024,512]
  const float* w_qkv  = (const float*)d_in[1];   // [512,1536]
  const float* w_proj = (const float*)d_in[2];   // [512,512]
  const float* b_proj = (const float*)d_in[3];   // [512]
  float* out = (float*)d_out;

  const int M = Bsz * NN;                        // 32768
  char* ws = (char*)d_ws;
  _Float16* xh    = (_Float16*)ws;                              // 33.55 MB
  _Float16* qkvh  = (_Float16*)(ws + 33554432);                 // 102.76 MB (1568-padded rows)
  _Float16* attnh = (_Float16*)(ws + 136314880);                // 33.55 MB
  _Float16* wqT   = (_Float16*)(ws + 169869312);                // 1.57 MB
  _Float16* wpT   = (_Float16*)(ws + 171442176);                // 0.52 MB

  // converts
  cvt_f32_f16<<<(M * Cc / 8 + 255) / 256, 256, 0, stream>>>(x, xh, M * Cc / 8);
  tcvt<<<(ROWS * Cc + 255) / 256, 256, 0, stream>>>(w_qkv, wqT, ROWS, Cc);
  tcvt<<<(Cc * Cc + 255) / 256, 256, 0, stream>>>(w_proj, wpT, Cc, Cc);

  // qkv = x @ w_qkv  (f16; 128x256 tiles: 6x256 = 1536 blocks, XCD-chunked;
  // ldc = 1568 padded)
  gemm_mfma<true, false><<<(ROWS / 256) * (M / 128), 512, 0, stream>>>(
      xh, wqT, nullptr, qkvh, ROWS / 256, ROWS, Cc, ROWSP);

  // local attention (h-paired, LDS-staged K/V, swapped max-free softmax)
  local_attn_mfma<<<(Hh / 2) * NHEAD * Bsz, 512, 0, stream>>>(qkvh, attnh);

  // out = attn @ w_proj + bias  (f32 out; 2x256 = 512 blocks, XCD-chunked)
  gemm_mfma<false, true><<<(Cc / 256) * (M / 128), 512, 0, stream>>>(
      attnh, wpT, b_proj, out, Cc / 256, Cc, Cc, Cc);
}

// Round 22
// 166.494 us; speedup vs baseline: 1.1024x; 1.0014x over previous
//
#include <hip/hip_runtime.h>

#define Bsz   32
#define Hh    8
#define Ww    128
#define Cc    512
#define NHEAD 8
#define HD    64
#define NN    1024
#define SCALE 0.125f
#define ROWS  1536
#define ROWSP 1568   // padded qkv row stride (halfs): 3136B -> L1 set-step 49, full coverage

typedef _Float16 f16x8 __attribute__((ext_vector_type(8)));
typedef float    f32x4 __attribute__((ext_vector_type(4)));

// ---------------------------------------------------------------------------
// async global->LDS, 16B per lane (linear dest = wave base + lane*16)
// ---------------------------------------------------------------------------
__device__ __forceinline__ void gload16(const _Float16* g, _Float16* l) {
#if __has_builtin(__builtin_amdgcn_global_load_lds)
  __builtin_amdgcn_global_load_lds(
      (const __attribute__((address_space(1))) unsigned int*)g,
      (__attribute__((address_space(3))) unsigned int*)l, 16, 0, 0);
#else
  *(uint4*)l = *(const uint4*)g;
#endif
}

// ---------------------------------------------------------------------------
// converts
// ---------------------------------------------------------------------------
__global__ __launch_bounds__(256) void cvt_f32_f16(
    const float* __restrict__ in, _Float16* __restrict__ out, int n8) {
  const int i = blockIdx.x * 256 + threadIdx.x;
  if (i < n8) {
    const float4 f0 = ((const float4*)in)[(size_t)i * 2];
    const float4 f1 = ((const float4*)in)[(size_t)i * 2 + 1];
    union { _Float16 h[8]; uint4 u; } pk;
    pk.h[0] = (_Float16)f0.x; pk.h[1] = (_Float16)f0.y;
    pk.h[2] = (_Float16)f0.z; pk.h[3] = (_Float16)f0.w;
    pk.h[4] = (_Float16)f1.x; pk.h[5] = (_Float16)f1.y;
    pk.h[6] = (_Float16)f1.z; pk.h[7] = (_Float16)f1.w;
    ((uint4*)out)[i] = pk.u;
  }
}

// out[n*K + k] = in[k*Nn + n]  (f32 -> f16 transpose)
__global__ __launch_bounds__(256) void tcvt(
    const float* __restrict__ in, _Float16* __restrict__ out, int Nn, int K) {
  const int id = blockIdx.x * 256 + threadIdx.x;
  if (id < Nn * K) {
    const int n = id / K, k = id - n * K;
    out[id] = (_Float16)in[(size_t)k * Nn + n];
  }
}

// ---------------------------------------------------------------------------
// 8-PHASE MFMA GEMM (T3+T4+T5 template, m201 structure). 256x256 tile,
// BK=64, 8 waves (2Mx4N), per-wave output 128x64 (rows wr*64+rh*128, cols
// wc*32+ch*128 -- rh/ch select the TILE half so halves free early). LDS =
// 2 dbuf x [256][64] x (A,B) = 128KB, 1 block/CU.
// Iteration computes K-tiles 2it (buf0, phases 0-3) and 2it+1 (buf1, 4-7),
// one C-quadrant (rh,ch) x K=64 per phase = 16 MFMA. Each phase stages ONE
// half-tile (2 gload_lds/thread) into the region freed 2 phases earlier:
//   stream s = 6 + it*8 + p; kt = s>>2, half = s&3 (A0,B0,A1,B1).
// Counted vmcnt (never 0 in steady state): vmcnt(4) at end of phases 3,7
// (newest 2 stagings may remain in flight); last iter's mid-wait = vmcnt(0).
// Granule swizzle (both-sides, r21-verified 0 conflicts): stored granule g
// of row r = global granule g^(r&7); reads XOR (rA&7) (row-invariant).
// B-fragments for ch=0/1 held in regs across rh phases -> 24 b128/K-tile.
// lgkmcnt(0)+sched_barrier(0) per phase (rule 18); setprio around MFMA (T5).
// ---------------------------------------------------------------------------
template<bool OUT_F16, bool HAS_BIAS>
__global__ __launch_bounds__(512, 2) void gemm8p(
    const _Float16* __restrict__ A,
    const _Float16* __restrict__ BT,
    const float* __restrict__ bias,
    void* __restrict__ Cout,
    int nbx, int Nn, int K, int ldc)
{
  __shared__ _Float16 As[2][256 * 64];   // 32KB per buf
  __shared__ _Float16 Bs[2][256 * 64];   // 32KB per buf

  const int wg    = blockIdx.x;
  const int chunk = gridDim.x >> 3;
  const int nid   = (wg & 7) * chunk + (wg >> 3);
  const int bn    = (nid % nbx) * 256;
  const int bm    = (nid / nbx) * 256;

  const int t  = threadIdx.x;
  const int l  = t & 63, wv = t >> 6;
  const int wr = wv >> 2, wc = wv & 3;

  f32x4 acc[8][4] = {};                  // [rh*4+i][ch*2+j]

  // staging coords: thread stages granules c=t and c=t+512 of a half-tile
  // (128 rows x 8 granules of 16B); row=c>>3, g=c&7; src gran = g^(row&7)
  const int srow0 = t >> 3;
  const int soff0 = (((t & 7) ^ (srow0 & 7)) << 3);
  const int srow1 = (t + 512) >> 3;
  const int soff1 = (((t & 7) ^ (srow1 & 7)) << 3);
  const int smax  = (K >> 4) - 1;        // last half-tile stream index

  auto stage = [&](int s) {
    if (s > smax) return;
    const int kt = s >> 2, h = s & 3;
    const int k0 = kt * 64, buf = kt & 1;
    _Float16* dst = ((h & 1) ? Bs[buf] : As[buf]) + (h >> 1) * 8192;
    const _Float16* src = (h & 1) ? (BT + (size_t)(bn + (h >> 1) * 128) * K)
                                  : (A  + (size_t)(bm + (h >> 1) * 128) * K);
    gload16(src + (size_t)srow0 * K + k0 + soff0, dst + t * 8);
    gload16(src + (size_t)srow1 * K + k0 + soff1, dst + t * 8 + 4096);
  };

  const int rA = l & 15, rx = rA & 7, kgb = l >> 4;

  auto loadA = [&](int buf, int rh, f16x8* aF) {
#pragma unroll
    for (int i = 0; i < 4; ++i) {
      const int row = rh * 128 + wr * 64 + i * 16 + rA;
#pragma unroll
      for (int kh = 0; kh < 2; ++kh)
        aF[i * 2 + kh] = *(const f16x8*)&As[buf][row * 64 + (((kgb + 4 * kh) ^ rx) << 3)];
    }
  };
  auto loadB = [&](int buf, int ch, f16x8* bF) {
#pragma unroll
    for (int j = 0; j < 2; ++j) {
      const int col = ch * 128 + wc * 32 + j * 16 + rA;
#pragma unroll
      for (int kh = 0; kh < 2; ++kh)
        bF[j * 2 + kh] = *(const f16x8*)&Bs[buf][col * 64 + (((kgb + 4 * kh) ^ rx) << 3)];
    }
  };
  auto mma16 = [&](const f16x8* aF, const f16x8* bF, int rh, int ch) {
    __builtin_amdgcn_s_setprio(1);
#pragma unroll
    for (int i = 0; i < 4; ++i)
#pragma unroll
      for (int j = 0; j < 2; ++j)
#pragma unroll
        for (int kh = 0; kh < 2; ++kh)
          acc[rh * 4 + i][ch * 2 + j] = __builtin_amdgcn_mfma_f32_16x16x32_f16(
              aF[i * 2 + kh], bF[j * 2 + kh], acc[rh * 4 + i][ch * 2 + j], 0, 0, 0);
    __builtin_amdgcn_s_setprio(0);
  };

#define PH_SYNC()                                          \
  __builtin_amdgcn_s_barrier();                            \
  asm volatile("s_waitcnt lgkmcnt(0)" ::: "memory");       \
  __builtin_amdgcn_sched_barrier(0)

  // ---- prologue: tile0 (s0-3) + tile1's A0,B0 (s4,s5); wait tile0 ----
  stage(0); stage(1); stage(2); stage(3); stage(4); stage(5);
  asm volatile("s_waitcnt vmcnt(4)" ::: "memory");
  __builtin_amdgcn_s_barrier();

  const int nIter = K / 128;
  f16x8 aF[8], bF0[4], bF1[4];

  for (int it = 0; it < nIter; ++it) {
    const int sb = 6 + it * 8;
    const bool lastIt = (it == nIter - 1);

    // ---- phases 0-3: K-tile 2it (buf 0) ----
    loadA(0, 0, aF); loadB(0, 0, bF0); stage(sb + 0);
    PH_SYNC(); mma16(aF, bF0, 0, 0); __builtin_amdgcn_s_barrier();

    loadB(0, 1, bF1); stage(sb + 1);
    PH_SYNC(); mma16(aF, bF1, 0, 1); __builtin_amdgcn_s_barrier();

    loadA(0, 1, aF); stage(sb + 2);
    PH_SYNC(); mma16(aF, bF0, 1, 0); __builtin_amdgcn_s_barrier();

    stage(sb + 3);
    PH_SYNC(); mma16(aF, bF1, 1, 1);
    if (lastIt) asm volatile("s_waitcnt vmcnt(0)" ::: "memory");
    else        asm volatile("s_waitcnt vmcnt(4)" ::: "memory");
    __builtin_amdgcn_s_barrier();

    // ---- phases 4-7: K-tile 2it+1 (buf 1) ----
    loadA(1, 0, aF); loadB(1, 0, bF0); stage(sb + 4);
    PH_SYNC(); mma16(aF, bF0, 0, 0); __builtin_amdgcn_s_barrier();

    loadB(1, 1, bF1); stage(sb + 5);
    PH_SYNC(); mma16(aF, bF1, 0, 1); __builtin_amdgcn_s_barrier();

    loadA(1, 1, aF); stage(sb + 6);
    PH_SYNC(); mma16(aF, bF0, 1, 0); __builtin_amdgcn_s_barrier();

    stage(sb + 7);
    PH_SYNC(); mma16(aF, bF1, 1, 1);
    if (!lastIt) asm volatile("s_waitcnt vmcnt(4)" ::: "memory");
    __builtin_amdgcn_s_barrier();
  }
#undef PH_SYNC

  // ---- epilogue ----
  const int lc = l & 15, lr4 = (l >> 4) * 4;
#pragma unroll
  for (int rh = 0; rh < 2; ++rh)
#pragma unroll
    for (int i = 0; i < 4; ++i) {
      const size_t row0 = (size_t)(bm + rh * 128 + wr * 64 + i * 16 + lr4);
#pragma unroll
      for (int ch = 0; ch < 2; ++ch)
#pragma unroll
        for (int j = 0; j < 2; ++j) {
          const int col = bn + ch * 128 + wc * 32 + j * 16 + lc;
          const float bv = HAS_BIAS ? bias[col] : 0.f;
#pragma unroll
          for (int r = 0; r < 4; ++r) {
            const float v = acc[rh * 4 + i][ch * 2 + j][r] + bv;
            if (OUT_F16)
              ((_Float16*)Cout)[(row0 + r) * ldc + col] = (_Float16)v;
            else
              ((float*)Cout)[(row0 + r) * ldc + col] = v;
          }
        }
    }
}

// ---------------------------------------------------------------------------
// MFMA local attention, h-paired (1024 blocks) + XCD-chunked. ALL per-wave
// fragment reads come from LDS (K via swizzled global_load_lds, V reg-
// transposed to Vsh[64][132]) -- round 18 verified this removes the L1
// scattered-fragment bottleneck. qkv rows padded to ROWSP=1568 halfs for
// full L1-set coverage. Swapped-QK + max-free softmax (P=exp(min(S,11)),
// one epilogue reduce). No fences; Pbuf wave-private. UNCHANGED from r18.
// ---------------------------------------------------------------------------
__global__ __launch_bounds__(512, 4) void local_attn_mfma(
    const _Float16* __restrict__ qkv, _Float16* __restrict__ outh)
{
  const int wg  = blockIdx.x;                 // 1024, 1-D
  const int nid = ((wg & 7) << 7) + (wg >> 3);
  const int hp = nid & 3, head = (nid >> 2) & 7, b = nid >> 5;
  const int h0 = hp * 2;

  const int t = threadIdx.x;
  const int wv = t >> 6, l = t & 63;
  const int g = l >> 4, c = l & 15;
  const int w0 = wv * 16;                     // wave's query-col tile base
  const int kb = min(max(w0 - 8, 0), 96);     // 8-aligned key tile base

  __shared__ _Float16 Ksh[8192];              // 128 cols x 64 halfs, chunk-swz
  __shared__ _Float16 Vsh[64 * 132];          // [d][132-pad cols]
  __shared__ _Float16 Pbuf[8][576];           // [wave][q*36 + kcol]

  const _Float16* qb = qkv + (size_t)b * NN * ROWSP;

  // ---- Q fragments (lane c holds Q[w0+c][k-slice]; used as B-operand) ----
  f16x8 qF[2][2];
#pragma unroll
  for (int hi = 0; hi < 2; ++hi) {
    const _Float16* Qg = qb + (size_t)((h0 + hi) * Ww + w0 + c) * ROWSP + head * HD;
    qF[hi][0] = *(const f16x8*)&Qg[g * 8];
    qF[hi][1] = *(const f16x8*)&Qg[32 + g * 8];
  }

  // ---- additive mask bias: kcol = kb+16tt+4g+r vs q = w0+c (h-indep) ----
  float mbias[2][4];
#pragma unroll
  for (int tt = 0; tt < 2; ++tt)
#pragma unroll
    for (int r = 0; r < 4; ++r) {
      const int kcol = kb + 16 * tt + 4 * g + r;
      const int qq   = w0 + c;
      mbias[tt][r] = (kcol >= qq - 5 && kcol <= qq + 5) ? 0.f : -1e30f;
    }

  const int r0 = max(0, h0 - 3), r1 = min(Hh - 1, h0 + 4);
  float s_part[2] = {0.f, 0.f};               // per-lane partial exp-sums
  f32x4 accO[2][4] = {};

  // V staging coords (threads t>=256: 4 cols x 8 d each)
  const int dd = t & 7, cg = (t & 255) >> 3;

  for (int kr = r0; kr <= r1; ++kr) {
    __syncthreads();                          // prev compute done with Ksh/Vsh
    if (t < 256) {
      const _Float16* Kg = qb + (size_t)(kr * Ww) * ROWSP + Cc + head * HD;
#pragma unroll
      for (int i = 0; i < 4; ++i) {
        const int o   = (i * 4 + wv) * 64 + l;       // linear chunk 0..1023
        const int col = o >> 3, dc = o & 7;
        gload16(Kg + (size_t)col * ROWSP + ((dc ^ (col & 7)) << 3), &Ksh[o * 8]);
      }
    } else {
      f16x8 vr[4];
      const _Float16* Vg = qb + (size_t)(kr * Ww + cg * 4) * ROWSP + 2 * Cc + head * HD + dd * 8;
#pragma unroll
      for (int i = 0; i < 4; ++i)
        vr[i] = *(const f16x8*)&Vg[(size_t)i * ROWSP];
#pragma unroll
      for (int e = 0; e < 8; ++e) {
        union { _Float16 hh[4]; uint2 u; } pk;
        pk.hh[0] = vr[0][e]; pk.hh[1] = vr[1][e];
        pk.hh[2] = vr[2][e]; pk.hh[3] = vr[3][e];
        *(uint2*)&Vsh[(dd * 8 + e) * 132 + cg * 4] = pk.u;
      }
    }
    __syncthreads();                          // Ksh/Vsh published (vmcnt+lgkm)

#pragma unroll
    for (int hi = 0; hi < 2; ++hi) {
      const int hq = h0 + hi;
      if (kr < hq - 3 || kr > hq + 3) continue;

      // ---- swapped QK^T from LDS: Ssw[kcol_local=4g+r (+16tt)][q=c] ----
      f32x4 accS[2] = {};
      __builtin_amdgcn_s_setprio(1);
#pragma unroll
      for (int tt = 0; tt < 2; ++tt) {
        const int col = kb + 16 * tt + c;
#pragma unroll
        for (int s = 0; s < 2; ++s) {
          const f16x8 kF = *(const f16x8*)&Ksh[col * 64 + (((s * 4 + g) ^ (c & 7)) << 3)];
          accS[tt] = __builtin_amdgcn_mfma_f32_16x16x32_f16(kF, qF[hi][s], accS[tt], 0, 0, 0);
        }
      }
      __builtin_amdgcn_s_setprio(0);

      // ---- max-free softmax: P = exp(min(S,11)), per-lane partial sum ----
#pragma unroll
      for (int tt = 0; tt < 2; ++tt) {
        float p0 = __expf(fminf(__builtin_fmaf(accS[tt][0], SCALE, mbias[tt][0]), 11.f));
        float p1 = __expf(fminf(__builtin_fmaf(accS[tt][1], SCALE, mbias[tt][1]), 11.f));
        float p2 = __expf(fminf(__builtin_fmaf(accS[tt][2], SCALE, mbias[tt][2]), 11.f));
        float p3 = __expf(fminf(__builtin_fmaf(accS[tt][3], SCALE, mbias[tt][3]), 11.f));
        s_part[hi] += (p0 + p1) + (p2 + p3);
        union { _Float16 hh[4]; uint2 u; } pk;
        pk.hh[0] = (_Float16)p0; pk.hh[1] = (_Float16)p1;
        pk.hh[2] = (_Float16)p2; pk.hh[3] = (_Float16)p3;
        *(uint2*)&Pbuf[wv][c * 36 + 16 * tt + 4 * g] = pk.u;
      }

      // ---- PV: O[q=4g+r][d=16jj+c] += P(16x32) * V(32x64-window) ----
      union { f16x8 v; uint2 u2[2]; } pF;
      {
        const _Float16* pp = &Pbuf[wv][c * 36 + g * 8];
        pF.u2[0] = *(const uint2*)pp;
        pF.u2[1] = *(const uint2*)(pp + 4);
      }
      __builtin_amdgcn_s_setprio(1);
#pragma unroll
      for (int jj = 0; jj < 4; ++jj) {
        union { f16x8 v; uint2 u2[2]; } vF;
        const _Float16* vp = &Vsh[(16 * jj + c) * 132 + kb + g * 8];
        vF.u2[0] = *(const uint2*)vp;
        vF.u2[1] = *(const uint2*)(vp + 4);
        accO[hi][jj] = __builtin_amdgcn_mfma_f32_16x16x32_f16(pF.v, vF.v, accO[hi][jj], 0, 0, 0);
      }
      __builtin_amdgcn_s_setprio(0);
    }
  }

  // ---- epilogue: one cross-lane reduce per hi, normalize, store ----
#pragma unroll
  for (int hi = 0; hi < 2; ++hi) {
    float s_run = s_part[hi];
    s_run += __shfl_xor(s_run, 16);
    s_run += __shfl_xor(s_run, 32);           // lanes (.,c) hold sum for query c
    _Float16* ob = outh + ((size_t)b * NN + (h0 + hi) * Ww + w0) * Cc + head * HD;
#pragma unroll
    for (int r = 0; r < 4; ++r) {
      const float sr  = __shfl(s_run, 4 * g + r, 16);
      const float inv = 1.f / sr;
      const int q = 4 * g + r;
#pragma unroll
      for (int jj = 0; jj < 4; ++jj)
        ob[(size_t)q * Cc + 16 * jj + c] = (_Float16)(accO[hi][jj][r] * inv);
    }
  }
}

// ---------------------------------------------------------------------------
extern "C" void kernel_launch(void* const* d_in, const int* in_sizes, int n_in,
                              void* d_out, int out_size, void* d_ws, size_t ws_size,
                              hipStream_t stream)
{
  const float* x      = (const float*)d_in[0];   // [32,1024,512]
  const float* w_qkv  = (const float*)d_in[1];   // [512,1536]
  const float* w_proj = (const float*)d_in[2];   // [512,512]
  const float* b_proj = (const float*)d_in[3];   // [512]
  float* out = (float*)d_out;

  const int M = Bsz * NN;                        // 32768
  char* ws = (char*)d_ws;
  _Float16* xh    = (_Float16*)ws;                              // 33.55 MB
  _Float16* qkvh  = (_Float16*)(ws + 33554432);                 // 102.76 MB (1568-padded rows)
  _Float16* attnh = (_Float16*)(ws + 136314880);                // 33.55 MB
  _Float16* wqT   = (_Float16*)(ws + 169869312);                // 1.57 MB
  _Float16* wpT   = (_Float16*)(ws + 171442176);                // 0.52 MB

  // converts
  cvt_f32_f16<<<(M * Cc / 8 + 255) / 256, 256, 0, stream>>>(x, xh, M * Cc / 8);
  tcvt<<<(ROWS * Cc + 255) / 256, 256, 0, stream>>>(w_qkv, wqT, ROWS, Cc);
  tcvt<<<(Cc * Cc + 255) / 256, 256, 0, stream>>>(w_proj, wpT, Cc, Cc);

  // qkv = x @ w_qkv  (f16; 256x256 tiles: 6x128 = 768 blocks, XCD-chunked;
  // ldc = 1568 padded)
  gemm8p<true, false><<<(ROWS / 256) * (M / 256), 512, 0, stream>>>(
      xh, wqT, nullptr, qkvh, ROWS / 256, ROWS, Cc, ROWSP);

  // local attention (h-paired, LDS-staged K/V, swapped max-free softmax)
  local_attn_mfma<<<(Hh / 2) * NHEAD * Bsz, 512, 0, stream>>>(qkvh, attnh);

  // out = attn @ w_proj + bias  (f32 out; 2x128 = 256 blocks, XCD-chunked)
  gemm8p<false, true><<<(Cc / 256) * (M / 256), 512, 0, stream>>>(
      attnh, wpT, b_proj, out, Cc / 256, Cc, Cc, Cc);
}